// Round 3
// baseline (116.789 us; speedup 1.0000x reference)
//
#include <hip/hip_runtime.h>
#include <stdint.h>

// Problem: B=8, S=1024, D=512, N=16 heads, K=32 head dim, H=W=32.
// I/O tensors are FLOAT32 (per reference + npz size evidence).
// Internal pipeline: bf16 MFMA with f32 accumulation.

typedef unsigned short u16;
typedef unsigned int   u32;
typedef float  f32x4  __attribute__((ext_vector_type(4)));
typedef float  f32x16 __attribute__((ext_vector_type(16)));
typedef __bf16 bf16x8 __attribute__((ext_vector_type(8)));

#define DEV static __device__ __forceinline__

DEV u16 f2bf(float f){ union { float f; u32 u; } c; c.f = f; u32 x = c.u;
                       return (u16)((x + 0x7fffu + ((x >> 16) & 1u)) >> 16); }
DEV bf16x8 as_bf8(uint4 v){ return __builtin_bit_cast(bf16x8, v); }

// ---------------------------------------------------------------------------
// K0: transpose 4 f32 weight matrices [512][512] -> bf16 WT [512][512]
// z=0..3 : Wq, Wk, Wv, Wo.   WT[col][row] = W[row][col]
// ---------------------------------------------------------------------------
__global__ __launch_bounds__(256) void k_wtrans(
    const float* __restrict__ Wq, const float* __restrict__ Wk,
    const float* __restrict__ Wv, const float* __restrict__ Wo,
    u16* __restrict__ WT)
{
  __shared__ float tile[64][65];
  const float* src = (blockIdx.z == 0) ? Wq : (blockIdx.z == 1) ? Wk
                   : (blockIdx.z == 2) ? Wv : Wo;
  u16* dst = WT + blockIdx.z * 512 * 512;
  const int t = threadIdx.x;
  const int r0 = blockIdx.y * 64, c0 = blockIdx.x * 64;
  #pragma unroll
  for (int p = 0; p < 4; p++){
    int r = p * 16 + (t >> 4), c = (t & 15) * 4;
    float4 v = *(const float4*)&src[(r0 + r) * 512 + c0 + c];
    tile[r][c+0] = v.x; tile[r][c+1] = v.y; tile[r][c+2] = v.z; tile[r][c+3] = v.w;
  }
  __syncthreads();
  #pragma unroll
  for (int p = 0; p < 2; p++){
    int rr = p * 32 + (t >> 3), cc = (t & 7) * 8;   // rr: out row (orig col)
    u32 d[4];
    #pragma unroll
    for (int j = 0; j < 4; j++){
      u32 lo = f2bf(tile[cc + 2*j][rr]);
      u32 hh = f2bf(tile[cc + 2*j + 1][rr]);
      d[j] = lo | (hh << 16);
    }
    uint4 v; v.x = d[0]; v.y = d[1]; v.z = d[2]; v.w = d[3];
    *(uint4*)&dst[(c0 + rr) * 512 + r0 + cc] = v;
  }
}

// ---------------------------------------------------------------------------
// K1: fused QKV projection. X(f32)[8192][512] x WT(bf16) ->
//     Q/K (bf16) [B,N,S,32], Vt (bf16) [B,N,32,S]
// blockIdx.z: 0=Q (scaled), 1=K, 2=V(transposed store). Tile 128x128, BK=64.
// ---------------------------------------------------------------------------
__global__ __launch_bounds__(256) void k_qkv(
    const float* __restrict__ X, const u16* __restrict__ WT,
    const float* __restrict__ bq, const float* __restrict__ bk, const float* __restrict__ bv,
    u16* __restrict__ Qo, u16* __restrict__ Ko, u16* __restrict__ Vt)
{
  __shared__ u16 sm[2][128][72];
  const int mode = blockIdx.z;
  const u16* W = WT + mode * (512 * 512);
  const int m0 = blockIdx.x * 128, n0 = blockIdx.y * 128;
  const int t = threadIdx.x, lane = t & 63, w = t >> 6;
  const int wr = w >> 1, wc = w & 1, lr = lane & 15, hi = lane >> 4;
  f32x4 acc[4][4] = {};
  for (int d0 = 0; d0 < 512; d0 += 64){
    // A tile: f32 -> bf16 convert during staging
    #pragma unroll
    for (int p = 0; p < 8; p++){
      int r = p * 16 + (t >> 4), c4 = (t & 15) * 4;
      float4 v = *(const float4*)&X[(m0 + r) * 512 + d0 + c4];
      uint2 pk2;
      pk2.x = (u32)f2bf(v.x) | ((u32)f2bf(v.y) << 16);
      pk2.y = (u32)f2bf(v.z) | ((u32)f2bf(v.w) << 16);
      *(uint2*)&sm[0][r][c4] = pk2;
    }
    // B tile: already bf16
    #pragma unroll
    for (int p = 0; p < 4; p++){
      int r = p * 32 + (t >> 3), ch = (t & 7) * 8;
      *(uint4*)&sm[1][r][ch] = *(const uint4*)&W[(n0 + r) * 512 + d0 + ch];
    }
    __syncthreads();
    #pragma unroll
    for (int kc = 0; kc < 2; kc++){
      bf16x8 a[4], b[4];
      #pragma unroll
      for (int i = 0; i < 4; i++){
        a[i] = as_bf8(*(const uint4*)&sm[0][wr*64 + i*16 + lr][kc*32 + hi*8]);
        b[i] = as_bf8(*(const uint4*)&sm[1][wc*64 + i*16 + lr][kc*32 + hi*8]);
      }
      #pragma unroll
      for (int i = 0; i < 4; i++)
        #pragma unroll
        for (int j = 0; j < 4; j++)
          acc[i][j] = __builtin_amdgcn_mfma_f32_16x16x32_bf16(a[i], b[j], acc[i][j], 0, 0, 0);
    }
    __syncthreads();
  }
  const float* bias = (mode == 0) ? bq : (mode == 1) ? bk : bv;
  float bv4[4];
  #pragma unroll
  for (int j = 0; j < 4; j++) bv4[j] = bias[n0 + wc*64 + j*16 + lr];

  if (mode < 2){
    u16* Out = (mode == 0) ? Qo : Ko;
    const float scale = (mode == 0) ? 0.17677669529663687f : 1.0f;
    u16* ep = &sm[0][0][0] + w * 4608;   // 64 x 72 region per wave
    #pragma unroll
    for (int i = 0; i < 4; i++)
      #pragma unroll
      for (int j = 0; j < 4; j++)
        #pragma unroll
        for (int r = 0; r < 4; r++){
          float v = (acc[i][j][r] + bv4[j]) * scale;
          ep[(i*16 + hi*4 + r) * 72 + j*16 + lr] = f2bf(v);
        }
    __syncthreads();   // order u16 stores vs uint4 readback
    #pragma unroll
    for (int p = 0; p < 8; p++){
      int rr = p * 8 + (lane >> 3), cc = (lane & 7) * 8;
      uint4 v = *(uint4*)&ep[rr * 72 + cc];
      int gm = m0 + wr*64 + rr;   // row -> (b,s)
      int gc = n0 + wc*64 + cc;   // col -> (n,k)
      int b = gm >> 10, s = gm & 1023, n = gc >> 5, kk = gc & 31;
      *(uint4*)&Out[((b*16 + n)*1024 + s)*32 + kk] = v;
    }
  } else {
    // V transposed: Vt[((b*16+n)*32 + k)*1024 + s]
    #pragma unroll
    for (int i = 0; i < 4; i++)
      #pragma unroll
      for (int j = 0; j < 4; j++){
        int gm = m0 + wr*64 + i*16 + hi*4;  // 4 consecutive s
        int gc = n0 + wc*64 + j*16 + lr;
        int b = gm >> 10, s = gm & 1023, n = gc >> 5, kk = gc & 31;
        u32 d0 = (u32)f2bf(acc[i][j][0] + bv4[j]) | ((u32)f2bf(acc[i][j][1] + bv4[j]) << 16);
        u32 d1 = (u32)f2bf(acc[i][j][2] + bv4[j]) | ((u32)f2bf(acc[i][j][3] + bv4[j]) << 16);
        uint2 vv; vv.x = d0; vv.y = d1;
        *(uint2*)&Vt[(((b*16 + n)*32 + kk) * 1024) + s] = vv;
      }
  }
}

// ---------------------------------------------------------------------------
// K2: attention. 1024 blocks: bid = (b*16+n)*8 + qtile. 4 waves x 32 q-rows.
// Swapped QK^T (mfma(K,Q) -> S^T, lane owns q=lane&31), online softmax,
// PV via mfma(V^T, P^T) -> out^T fragments.
// ---------------------------------------------------------------------------
__global__ __launch_bounds__(256) void k_attn(
    const u16* __restrict__ Q, const u16* __restrict__ Kg,
    const u16* __restrict__ Vt, const float* __restrict__ relb,
    u16* __restrict__ AO)
{
  __shared__ float bias_s[63 * 63];
  __shared__ u16 ks[64][40];   // K tile [64 t][32 k], 80 B rows (pad 8)
  __shared__ u16 vs[32][72];   // V^T tile [32 k][64 t], 144 B rows (pad 8)
  const int t = threadIdx.x, lane = t & 63, w = t >> 6;
  const int hi = lane >> 5, lq = lane & 31;
  const int bid = blockIdx.x;
  const int qt = bid & 7, bn = bid >> 3, n = bn & 15;
  const int q0 = qt * 128 + w * 32;
  const u16* Qp = Q  + (bn * 1024 + q0) * 32;
  const u16* Kp = Kg + bn * 1024 * 32;
  const u16* Vp = Vt + bn * 32 * 1024;
  const float* rb = relb + n * 63 * 63;
  for (int i = t; i < 63 * 63; i += 256) bias_s[i] = rb[i];

  bf16x8 qf[2];
  #pragma unroll
  for (int kc = 0; kc < 2; kc++)
    qf[kc] = as_bf8(*(const uint4*)&Qp[lq*32 + kc*16 + hi*8]);
  const int h_q = q0 >> 5;

  f32x16 oacc = {};
  float mrun = -1.0e30f, lsum = 0.f;

  for (int t0 = 0; t0 < 1024; t0 += 64){
    {
      int r = t >> 2, ch = (t & 3) * 8;
      *(uint4*)&ks[r][ch] = *(const uint4*)&Kp[(t0 + r) * 32 + ch];
      int r2 = t >> 3, c2 = (t & 7) * 8;
      *(uint4*)&vs[r2][c2] = *(const uint4*)&Vp[r2 * 1024 + t0 + c2];
    }
    __syncthreads();

    float p[32];
    float tmax = -1.0e30f;
    #pragma unroll
    for (int ts = 0; ts < 2; ts++){
      f32x16 c = {};
      bf16x8 kf0 = as_bf8(*(const uint4*)&ks[ts*32 + lq][hi*8]);
      bf16x8 kf1 = as_bf8(*(const uint4*)&ks[ts*32 + lq][16 + hi*8]);
      c = __builtin_amdgcn_mfma_f32_32x32x16_bf16(kf0, qf[0], c, 0, 0, 0);
      c = __builtin_amdgcn_mfma_f32_32x32x16_bf16(kf1, qf[1], c, 0, 0, 0);
      const int dh = h_q - (t0 >> 5) - ts + 31;                // wave-uniform
      const int bbase = dh * 63 + 31 + lq - hi * 4;            // dw = bbase - tl
      #pragma unroll
      for (int r = 0; r < 16; r++){
        int tl = (r & 3) + 8 * (r >> 2);
        float v = c[r] + bias_s[bbase - tl];
        p[ts*16 + r] = v;
        tmax = fmaxf(tmax, v);
      }
    }
    tmax = fmaxf(tmax, __shfl_xor(tmax, 32));
    float mn = fmaxf(mrun, tmax);
    float alpha = __expf(mrun - mn);
    mrun = mn;
    lsum *= alpha;
    #pragma unroll
    for (int r = 0; r < 16; r++) oacc[r] *= alpha;
    #pragma unroll
    for (int i = 0; i < 32; i++){ p[i] = __expf(p[i] - mn); lsum += p[i]; }

    u32 pk[16], ot[16];
    #pragma unroll
    for (int e = 0; e < 16; e++)
      pk[e] = (u32)f2bf(p[2*e]) | ((u32)f2bf(p[2*e + 1]) << 16);
    #pragma unroll
    for (int e = 0; e < 16; e++)
      ot[e] = (u32)__shfl_xor((int)pk[e], 32);

    #pragma unroll
    for (int tc = 0; tc < 4; tc++){
      int base = (tc >> 1) * 8 + (tc & 1) * 4;
      uint4 bb;
      if (hi == 0){ bb.x = pk[base];   bb.y = pk[base+1]; bb.z = ot[base];   bb.w = ot[base+1]; }
      else        { bb.x = ot[base+2]; bb.y = ot[base+3]; bb.z = pk[base+2]; bb.w = pk[base+3]; }
      bf16x8 pb = as_bf8(bb);
      bf16x8 vf = as_bf8(*(const uint4*)&vs[lq][tc*16 + hi*8]);
      oacc = __builtin_amdgcn_mfma_f32_32x32x16_bf16(vf, pb, oacc, 0, 0, 0);
    }
    __syncthreads();
  }
  lsum += __shfl_xor(lsum, 32);
  float inv = 1.0f / lsum;
  const int b = bn >> 4;
  u16* op = AO + ((b * 1024 + q0 + lq) * 16 + n) * 32;
  #pragma unroll
  for (int g = 0; g < 4; g++){
    u32 d0 = (u32)f2bf(oacc[g*4+0] * inv) | ((u32)f2bf(oacc[g*4+1] * inv) << 16);
    u32 d1 = (u32)f2bf(oacc[g*4+2] * inv) | ((u32)f2bf(oacc[g*4+3] * inv) << 16);
    uint2 vv; vv.x = d0; vv.y = d1;
    *(uint2*)&op[g*8 + hi*4] = vv;
  }
}

// ---------------------------------------------------------------------------
// K3: output projection. attn(bf16) [8192][512] x WoT(bf16) -> out(F32) + bo
// ---------------------------------------------------------------------------
__global__ __launch_bounds__(256) void k_out(
    const u16* __restrict__ Ain, const u16* __restrict__ WoT,
    const float* __restrict__ bo, float* __restrict__ Out)
{
  __shared__ u16 sm[2][128][72];
  const int m0 = blockIdx.x * 128, n0 = blockIdx.y * 128;
  const int t = threadIdx.x, lane = t & 63, w = t >> 6;
  const int wr = w >> 1, wc = w & 1, lr = lane & 15, hi = lane >> 4;
  f32x4 acc[4][4] = {};
  for (int d0 = 0; d0 < 512; d0 += 64){
    #pragma unroll
    for (int p = 0; p < 4; p++){
      int r = p * 32 + (t >> 3), ch = (t & 7) * 8;
      *(uint4*)&sm[0][r][ch] = *(const uint4*)&Ain[(m0 + r) * 512 + d0 + ch];
      *(uint4*)&sm[1][r][ch] = *(const uint4*)&WoT[(n0 + r) * 512 + d0 + ch];
    }
    __syncthreads();
    #pragma unroll
    for (int kc = 0; kc < 2; kc++){
      bf16x8 a[4], b[4];
      #pragma unroll
      for (int i = 0; i < 4; i++){
        a[i] = as_bf8(*(const uint4*)&sm[0][wr*64 + i*16 + lr][kc*32 + hi*8]);
        b[i] = as_bf8(*(const uint4*)&sm[1][wc*64 + i*16 + lr][kc*32 + hi*8]);
      }
      #pragma unroll
      for (int i = 0; i < 4; i++)
        #pragma unroll
        for (int j = 0; j < 4; j++)
          acc[i][j] = __builtin_amdgcn_mfma_f32_16x16x32_bf16(a[i], b[j], acc[i][j], 0, 0, 0);
    }
    __syncthreads();
  }
  float bv4[4];
  #pragma unroll
  for (int j = 0; j < 4; j++) bv4[j] = bo[n0 + wc*64 + j*16 + lr];
  // direct f32 stores (output dtype f32)
  #pragma unroll
  for (int i = 0; i < 4; i++)
    #pragma unroll
    for (int j = 0; j < 4; j++)
      #pragma unroll
      for (int r = 0; r < 4; r++)
        Out[(m0 + wr*64 + i*16 + hi*4 + r) * 512 + n0 + wc*64 + j*16 + lr]
            = acc[i][j][r] + bv4[j];
}

// ---------------------------------------------------------------------------
extern "C" void kernel_launch(void* const* d_in, const int* in_sizes, int n_in,
                              void* d_out, int out_size, void* d_ws, size_t ws_size,
                              hipStream_t stream)
{
  const float* query = (const float*)d_in[0];
  const float* Wq    = (const float*)d_in[1];
  const float* bq    = (const float*)d_in[2];
  const float* Wk    = (const float*)d_in[3];
  const float* bk    = (const float*)d_in[4];
  const float* Wv    = (const float*)d_in[5];
  const float* bv    = (const float*)d_in[6];
  const float* Wo    = (const float*)d_in[7];
  const float* bo    = (const float*)d_in[8];
  const float* relb  = (const float*)d_in[9];
  float* out = (float*)d_out;

  u16* WT  = (u16*)d_ws;                       // 4 * 512*512 bf16
  u16* Qw  = WT  + 4 * 512 * 512;              // 8*16*1024*32 bf16 each
  u16* Kw  = Qw  + 8 * 16 * 1024 * 32;
  u16* Vtw = Kw  + 8 * 16 * 1024 * 32;
  u16* Aw  = Vtw + 8 * 16 * 1024 * 32;

  k_wtrans<<<dim3(8, 8, 4), dim3(256), 0, stream>>>(Wq, Wk, Wv, Wo, WT);
  k_qkv  <<<dim3(64, 4, 3), dim3(256), 0, stream>>>(query, WT, bq, bk, bv, Qw, Kw, Vtw);
  k_attn <<<dim3(1024),     dim3(256), 0, stream>>>(Qw, Kw, Vtw, relb, Aw);
  k_out  <<<dim3(64, 4),    dim3(256), 0, stream>>>(Aw, WT + 3 * 512 * 512, bo, out);
}

// Round 4
// 95.840 us; speedup vs baseline: 1.2186x; 1.2186x over previous
//
#include <hip/hip_runtime.h>
#include <stdint.h>

// Problem: B=8, S=1024, D=512, N=16 heads, K=32 head dim, H=W=32.
// I/O tensors FLOAT32; internal pipeline bf16 MFMA with f32 accumulation.

typedef unsigned short u16;
typedef unsigned int   u32;
typedef float  f32x4  __attribute__((ext_vector_type(4)));
typedef float  f32x16 __attribute__((ext_vector_type(16)));
typedef __bf16 bf16x8 __attribute__((ext_vector_type(8)));

#define DEV static __device__ __forceinline__

#if __has_builtin(__builtin_amdgcn_exp2f)
#define EXP2(x) __builtin_amdgcn_exp2f(x)
#else
#define EXP2(x) exp2f(x)
#endif

DEV u16 f2bf(float f){ union { float f; u32 u; } c; c.f = f; u32 x = c.u;
                       return (u16)((x + 0x7fffu + ((x >> 16) & 1u)) >> 16); }
// HW packed f32->bf16 (RNE), 1 instruction (guide T12/m240: no builtin, use asm)
DEV u32 cvtpk(float lo, float hh){
  u32 r; asm("v_cvt_pk_bf16_f32 %0, %1, %2" : "=v"(r) : "v"(lo), "v"(hh));
  return r;
}
// v_permlane32_swap_b32: exchanges upper 32 lanes of a with lower 32 lanes of b
// => a' = (loA||loB), b' = (hiA||hiB)
DEV void plswap(u32 &a, u32 &b){
  asm("v_permlane32_swap_b32 %0, %1" : "+v"(a), "+v"(b));
}
DEV bf16x8 as_bf8(uint4 v){ return __builtin_bit_cast(bf16x8, v); }

#define LOG2E 1.4426950408889634f

// ---------------------------------------------------------------------------
// K0: transpose 4 f32 weight matrices [512][512] -> bf16 WT [512][512]
// ---------------------------------------------------------------------------
__global__ __launch_bounds__(256) void k_wtrans(
    const float* __restrict__ Wq, const float* __restrict__ Wk,
    const float* __restrict__ Wv, const float* __restrict__ Wo,
    u16* __restrict__ WT)
{
  __shared__ float tile[64][65];
  const float* src = (blockIdx.z == 0) ? Wq : (blockIdx.z == 1) ? Wk
                   : (blockIdx.z == 2) ? Wv : Wo;
  u16* dst = WT + blockIdx.z * 512 * 512;
  const int t = threadIdx.x;
  const int r0 = blockIdx.y * 64, c0 = blockIdx.x * 64;
  #pragma unroll
  for (int p = 0; p < 4; p++){
    int r = p * 16 + (t >> 4), c = (t & 15) * 4;
    float4 v = *(const float4*)&src[(r0 + r) * 512 + c0 + c];
    tile[r][c+0] = v.x; tile[r][c+1] = v.y; tile[r][c+2] = v.z; tile[r][c+3] = v.w;
  }
  __syncthreads();
  #pragma unroll
  for (int p = 0; p < 2; p++){
    int rr = p * 32 + (t >> 3), cc = (t & 7) * 8;
    uint4 v;
    v.x = cvtpk(tile[cc+0][rr], tile[cc+1][rr]);
    v.y = cvtpk(tile[cc+2][rr], tile[cc+3][rr]);
    v.z = cvtpk(tile[cc+4][rr], tile[cc+5][rr]);
    v.w = cvtpk(tile[cc+6][rr], tile[cc+7][rr]);
    *(uint4*)&dst[(c0 + rr) * 512 + r0 + cc] = v;
  }
}

// ---------------------------------------------------------------------------
// K1: fused QKV projection. X(f32)[8192][512] x WT(bf16) ->
//     Q/K (bf16) [B,N,S,32], Vt (bf16) [B,N,32,S].  Q pre-scaled by
//     q_scale*log2e (exp2-domain softmax downstream).
// ---------------------------------------------------------------------------
__global__ __launch_bounds__(256) void k_qkv(
    const float* __restrict__ X, const u16* __restrict__ WT,
    const float* __restrict__ bq, const float* __restrict__ bk, const float* __restrict__ bv,
    u16* __restrict__ Qo, u16* __restrict__ Ko, u16* __restrict__ Vt)
{
  __shared__ u16 sm[2][128][72];
  const int mode = blockIdx.z;
  const u16* W = WT + mode * (512 * 512);
  const int m0 = blockIdx.x * 128, n0 = blockIdx.y * 128;
  const int t = threadIdx.x, lane = t & 63, w = t >> 6;
  const int wr = w >> 1, wc = w & 1, lr = lane & 15, hi = lane >> 4;
  f32x4 acc[4][4] = {};
  for (int d0 = 0; d0 < 512; d0 += 64){
    // A tile: f32 -> bf16 convert during staging (HW cvt_pk)
    #pragma unroll
    for (int p = 0; p < 8; p++){
      int r = p * 16 + (t >> 4), c4 = (t & 15) * 4;
      float4 v = *(const float4*)&X[(m0 + r) * 512 + d0 + c4];
      uint2 pk2; pk2.x = cvtpk(v.x, v.y); pk2.y = cvtpk(v.z, v.w);
      *(uint2*)&sm[0][r][c4] = pk2;
    }
    #pragma unroll
    for (int p = 0; p < 4; p++){
      int r = p * 32 + (t >> 3), ch = (t & 7) * 8;
      *(uint4*)&sm[1][r][ch] = *(const uint4*)&W[(n0 + r) * 512 + d0 + ch];
    }
    __syncthreads();
    #pragma unroll
    for (int kc = 0; kc < 2; kc++){
      bf16x8 a[4], b[4];
      #pragma unroll
      for (int i = 0; i < 4; i++){
        a[i] = as_bf8(*(const uint4*)&sm[0][wr*64 + i*16 + lr][kc*32 + hi*8]);
        b[i] = as_bf8(*(const uint4*)&sm[1][wc*64 + i*16 + lr][kc*32 + hi*8]);
      }
      #pragma unroll
      for (int i = 0; i < 4; i++)
        #pragma unroll
        for (int j = 0; j < 4; j++)
          acc[i][j] = __builtin_amdgcn_mfma_f32_16x16x32_bf16(a[i], b[j], acc[i][j], 0, 0, 0);
    }
    __syncthreads();
  }
  const float* bias = (mode == 0) ? bq : (mode == 1) ? bk : bv;
  float bv4[4];
  #pragma unroll
  for (int j = 0; j < 4; j++) bv4[j] = bias[n0 + wc*64 + j*16 + lr];

  if (mode < 2){
    u16* Out = (mode == 0) ? Qo : Ko;
    const float scale = (mode == 0) ? (0.17677669529663687f * LOG2E) : 1.0f;
    u16* ep = &sm[0][0][0] + w * 4608;   // 64 x 72 region per wave
    #pragma unroll
    for (int i = 0; i < 4; i++)
      #pragma unroll
      for (int j = 0; j < 4; j++)
        #pragma unroll
        for (int r = 0; r < 4; r++){
          float v = (acc[i][j][r] + bv4[j]) * scale;
          ep[(i*16 + hi*4 + r) * 72 + j*16 + lr] = f2bf(v);
        }
    __syncthreads();   // order u16 stores vs uint4 readback
    #pragma unroll
    for (int p = 0; p < 8; p++){
      int rr = p * 8 + (lane >> 3), cc = (lane & 7) * 8;
      uint4 v = *(uint4*)&ep[rr * 72 + cc];
      int gm = m0 + wr*64 + rr;   // row -> (b,s)
      int gc = n0 + wc*64 + cc;   // col -> (n,k)
      int b = gm >> 10, s = gm & 1023, n = gc >> 5, kk = gc & 31;
      *(uint4*)&Out[((b*16 + n)*1024 + s)*32 + kk] = v;
    }
  } else {
    // V transposed: Vt[((b*16+n)*32 + k)*1024 + s]
    #pragma unroll
    for (int i = 0; i < 4; i++)
      #pragma unroll
      for (int j = 0; j < 4; j++){
        int gm = m0 + wr*64 + i*16 + hi*4;  // 4 consecutive s
        int gc = n0 + wc*64 + j*16 + lr;
        int b = gm >> 10, s = gm & 1023, n = gc >> 5, kk = gc & 31;
        uint2 vv;
        vv.x = cvtpk(acc[i][j][0] + bv4[j], acc[i][j][1] + bv4[j]);
        vv.y = cvtpk(acc[i][j][2] + bv4[j], acc[i][j][3] + bv4[j]);
        *(uint2*)&Vt[(((b*16 + n)*32 + kk) * 1024) + s] = vv;
      }
  }
}

// ---------------------------------------------------------------------------
// K2: attention. 1024 blocks (XCD-swizzled): bid = (b*16+n)*8 + qtile.
// 4 waves x 32 q-rows. No K/V LDS staging (L2-resident), no barriers in loop.
// Swapped QK^T (mfma(K,Q) -> S^T, lane owns q=lane&31). No-max exp2 softmax
// (logits bounded; C=8 folded into bias). P pack via cvt_pk + permlane32_swap.
// ---------------------------------------------------------------------------
__global__ __launch_bounds__(256) void k_attn(
    const u16* __restrict__ Q, const u16* __restrict__ Kg,
    const u16* __restrict__ Vt, const float* __restrict__ relb,
    u16* __restrict__ AO)
{
  __shared__ float bias_s[63 * 63];
  const int t = threadIdx.x, lane = t & 63, w = t >> 6;
  const int hi = lane >> 5, lq = lane & 31;
  const int bid = ((blockIdx.x & 7) << 7) | (blockIdx.x >> 3);  // XCD swizzle
  const int qt = bid & 7, bn = bid >> 3, n = bn & 15;
  const int q0 = qt * 128 + w * 32;
  const u16* Qp = Q  + (bn * 1024 + q0) * 32;
  const u16* Kp = Kg + bn * 1024 * 32;
  const u16* Vp = Vt + bn * 32 * 1024;
  const float* rb = relb + n * 63 * 63;
  // bias in exp2 domain, minus safety C=8 (softmax shift-invariant)
  for (int i = t; i < 63 * 63; i += 256) bias_s[i] = rb[i] * LOG2E - 8.0f;

  bf16x8 qf[2];
  #pragma unroll
  for (int kc = 0; kc < 2; kc++)
    qf[kc] = as_bf8(*(const uint4*)&Qp[lq*32 + kc*16 + hi*8]);
  const int h_q = q0 >> 5;
  __syncthreads();

  f32x16 oacc = {};
  float ls0 = 0.f, ls1 = 0.f;

  for (int t0 = 0; t0 < 1024; t0 += 64){
    uint4 kv[4], vv[4];
    #pragma unroll
    for (int ts = 0; ts < 2; ts++){
      kv[ts*2+0] = *(const uint4*)&Kp[(t0 + ts*32 + lq)*32 + hi*8];
      kv[ts*2+1] = *(const uint4*)&Kp[(t0 + ts*32 + lq)*32 + 16 + hi*8];
    }
    #pragma unroll
    for (int tc = 0; tc < 4; tc++)
      vv[tc] = *(const uint4*)&Vp[lq*1024 + t0 + tc*16 + hi*8];

    u32 pk[16];
    #pragma unroll
    for (int ts = 0; ts < 2; ts++){
      f32x16 c = {};
      c = __builtin_amdgcn_mfma_f32_32x32x16_bf16(as_bf8(kv[ts*2+0]), qf[0], c, 0, 0, 0);
      c = __builtin_amdgcn_mfma_f32_32x32x16_bf16(as_bf8(kv[ts*2+1]), qf[1], c, 0, 0, 0);
      const int dh = h_q - (t0 >> 5) - ts + 31;                // wave-uniform
      const int bbase = dh * 63 + 31 + lq - hi * 4;            // dw = bbase - tl
      #pragma unroll
      for (int r = 0; r < 16; r += 2){
        int tl = (r & 3) + 8 * (r >> 2);
        float v0 = EXP2(c[r]   + bias_s[bbase - tl]);
        float v1 = EXP2(c[r+1] + bias_s[bbase - tl - 1]);
        ls0 += v0; ls1 += v1;
        pk[ts*8 + (r >> 1)] = cvtpk(v0, v1);
      }
    }
    // PV: B-fragment for tc from pairs (4tc,4tc+2),(4tc+1,4tc+3) via permlane swap
    #pragma unroll
    for (int tc = 0; tc < 4; tc++){
      u32 a0 = pk[tc*4+0], b0 = pk[tc*4+2];
      u32 a1 = pk[tc*4+1], b1 = pk[tc*4+3];
      plswap(a0, b0);
      plswap(a1, b1);
      uint4 bb; bb.x = a0; bb.y = a1; bb.z = b0; bb.w = b1;
      oacc = __builtin_amdgcn_mfma_f32_32x32x16_bf16(as_bf8(vv[tc]), as_bf8(bb), oacc, 0, 0, 0);
    }
  }
  float lsum = ls0 + ls1;
  lsum += __shfl_xor(lsum, 32);
  float inv = 1.0f / lsum;
  const int b = bn >> 4;
  u16* op = AO + ((b * 1024 + q0 + lq) * 16 + n) * 32;
  #pragma unroll
  for (int g = 0; g < 4; g++){
    uint2 vv2;
    vv2.x = cvtpk(oacc[g*4+0] * inv, oacc[g*4+1] * inv);
    vv2.y = cvtpk(oacc[g*4+2] * inv, oacc[g*4+3] * inv);
    *(uint2*)&op[g*8 + hi*4] = vv2;
  }
}

// ---------------------------------------------------------------------------
// K3: output projection. attn(bf16) [8192][512] x WoT(bf16) -> out(F32) + bo
// ---------------------------------------------------------------------------
__global__ __launch_bounds__(256) void k_out(
    const u16* __restrict__ Ain, const u16* __restrict__ WoT,
    const float* __restrict__ bo, float* __restrict__ Out)
{
  __shared__ u16 sm[2][128][72];
  const int m0 = blockIdx.x * 128, n0 = blockIdx.y * 128;
  const int t = threadIdx.x, lane = t & 63, w = t >> 6;
  const int wr = w >> 1, wc = w & 1, lr = lane & 15, hi = lane >> 4;
  f32x4 acc[4][4] = {};
  for (int d0 = 0; d0 < 512; d0 += 64){
    #pragma unroll
    for (int p = 0; p < 4; p++){
      int r = p * 32 + (t >> 3), ch = (t & 7) * 8;
      *(uint4*)&sm[0][r][ch] = *(const uint4*)&Ain[(m0 + r) * 512 + d0 + ch];
      *(uint4*)&sm[1][r][ch] = *(const uint4*)&WoT[(n0 + r) * 512 + d0 + ch];
    }
    __syncthreads();
    #pragma unroll
    for (int kc = 0; kc < 2; kc++){
      bf16x8 a[4], b[4];
      #pragma unroll
      for (int i = 0; i < 4; i++){
        a[i] = as_bf8(*(const uint4*)&sm[0][wr*64 + i*16 + lr][kc*32 + hi*8]);
        b[i] = as_bf8(*(const uint4*)&sm[1][wc*64 + i*16 + lr][kc*32 + hi*8]);
      }
      #pragma unroll
      for (int i = 0; i < 4; i++)
        #pragma unroll
        for (int j = 0; j < 4; j++)
          acc[i][j] = __builtin_amdgcn_mfma_f32_16x16x32_bf16(a[i], b[j], acc[i][j], 0, 0, 0);
    }
    __syncthreads();
  }
  float bv4[4];
  #pragma unroll
  for (int j = 0; j < 4; j++) bv4[j] = bo[n0 + wc*64 + j*16 + lr];
  #pragma unroll
  for (int i = 0; i < 4; i++)
    #pragma unroll
    for (int j = 0; j < 4; j++)
      #pragma unroll
      for (int r = 0; r < 4; r++)
        Out[(m0 + wr*64 + i*16 + hi*4 + r) * 512 + n0 + wc*64 + j*16 + lr]
            = acc[i][j][r] + bv4[j];
}

// ---------------------------------------------------------------------------
extern "C" void kernel_launch(void* const* d_in, const int* in_sizes, int n_in,
                              void* d_out, int out_size, void* d_ws, size_t ws_size,
                              hipStream_t stream)
{
  const float* query = (const float*)d_in[0];
  const float* Wq    = (const float*)d_in[1];
  const float* bq    = (const float*)d_in[2];
  const float* Wk    = (const float*)d_in[3];
  const float* bk    = (const float*)d_in[4];
  const float* Wv    = (const float*)d_in[5];
  const float* bv    = (const float*)d_in[6];
  const float* Wo    = (const float*)d_in[7];
  const float* bo    = (const float*)d_in[8];
  const float* relb  = (const float*)d_in[9];
  float* out = (float*)d_out;

  u16* WT  = (u16*)d_ws;                       // 4 * 512*512 bf16
  u16* Qw  = WT  + 4 * 512 * 512;              // 8*16*1024*32 bf16 each
  u16* Kw  = Qw  + 8 * 16 * 1024 * 32;
  u16* Vtw = Kw  + 8 * 16 * 1024 * 32;
  u16* Aw  = Vtw + 8 * 16 * 1024 * 32;

  k_wtrans<<<dim3(8, 8, 4), dim3(256), 0, stream>>>(Wq, Wk, Wv, Wo, WT);
  k_qkv  <<<dim3(64, 4, 3), dim3(256), 0, stream>>>(query, WT, bq, bk, bv, Qw, Kw, Vtw);
  k_attn <<<dim3(1024),     dim3(256), 0, stream>>>(Qw, Kw, Vtw, relb, Aw);
  k_out  <<<dim3(64, 4),    dim3(256), 0, stream>>>(Aw, WT + 3 * 512 * 512, bo, out);
}

// Round 5
// 94.916 us; speedup vs baseline: 1.2304x; 1.0097x over previous
//
#include <hip/hip_runtime.h>
#include <stdint.h>

// Problem: B=8, S=1024, D=512, N=16 heads, K=32 head dim, H=W=32.
// I/O tensors FLOAT32; internal pipeline bf16 MFMA with f32 accumulation.

typedef unsigned short u16;
typedef unsigned int   u32;
typedef float  f32x4  __attribute__((ext_vector_type(4)));
typedef float  f32x16 __attribute__((ext_vector_type(16)));
typedef __bf16 bf16x8 __attribute__((ext_vector_type(8)));

#define DEV static __device__ __forceinline__

#if __has_builtin(__builtin_amdgcn_exp2f)
#define EXP2(x) __builtin_amdgcn_exp2f(x)
#else
#define EXP2(x) exp2f(x)
#endif

DEV u16 f2bf(float f){ union { float f; u32 u; } c; c.f = f; u32 x = c.u;
                       return (u16)((x + 0x7fffu + ((x >> 16) & 1u)) >> 16); }
// HW packed f32->bf16 (RNE), 1 instruction
DEV u32 cvtpk(float lo, float hh){
  u32 r; asm("v_cvt_pk_bf16_f32 %0, %1, %2" : "=v"(r) : "v"(lo), "v"(hh));
  return r;
}
// v_permlane32_swap_b32: a' = (loA||loB), b' = (hiA||hiB)
DEV void plswap(u32 &a, u32 &b){
  asm("v_permlane32_swap_b32 %0, %1" : "+v"(a), "+v"(b));
}
DEV bf16x8 as_bf8(uint4 v){ return __builtin_bit_cast(bf16x8, v); }

#define LOG2E 1.4426950408889634f

// ---------------------------------------------------------------------------
// K0: transpose 4 f32 weight matrices [512][512] -> bf16 WT [512][512]
// ---------------------------------------------------------------------------
__global__ __launch_bounds__(256) void k_wtrans(
    const float* __restrict__ Wq, const float* __restrict__ Wk,
    const float* __restrict__ Wv, const float* __restrict__ Wo,
    u16* __restrict__ WT)
{
  __shared__ float tile[64][65];
  const float* src = (blockIdx.z == 0) ? Wq : (blockIdx.z == 1) ? Wk
                   : (blockIdx.z == 2) ? Wv : Wo;
  u16* dst = WT + blockIdx.z * 512 * 512;
  const int t = threadIdx.x;
  const int r0 = blockIdx.y * 64, c0 = blockIdx.x * 64;
  #pragma unroll
  for (int p = 0; p < 4; p++){
    int r = p * 16 + (t >> 4), c = (t & 15) * 4;
    float4 v = *(const float4*)&src[(r0 + r) * 512 + c0 + c];
    tile[r][c+0] = v.x; tile[r][c+1] = v.y; tile[r][c+2] = v.z; tile[r][c+3] = v.w;
  }
  __syncthreads();
  #pragma unroll
  for (int p = 0; p < 2; p++){
    int rr = p * 32 + (t >> 3), cc = (t & 7) * 8;
    uint4 v;
    v.x = cvtpk(tile[cc+0][rr], tile[cc+1][rr]);
    v.y = cvtpk(tile[cc+2][rr], tile[cc+3][rr]);
    v.z = cvtpk(tile[cc+4][rr], tile[cc+5][rr]);
    v.w = cvtpk(tile[cc+6][rr], tile[cc+7][rr]);
    *(uint4*)&dst[(c0 + rr) * 512 + r0 + cc] = v;
  }
}

// ---------------------------------------------------------------------------
// K1: fused QKV projection. X(f32)[8192][512] x WT(bf16) ->
//     Q/K (bf16) [B,N,S,32], Vt (bf16) [B,N,32,S].  Q pre-scaled by
//     q_scale*log2e (exp2-domain softmax downstream).
// ---------------------------------------------------------------------------
__global__ __launch_bounds__(256) void k_qkv(
    const float* __restrict__ X, const u16* __restrict__ WT,
    const float* __restrict__ bq, const float* __restrict__ bk, const float* __restrict__ bv,
    u16* __restrict__ Qo, u16* __restrict__ Ko, u16* __restrict__ Vt)
{
  __shared__ u16 sm[2][128][72];
  const int mode = blockIdx.z;
  const u16* W = WT + mode * (512 * 512);
  const int m0 = blockIdx.x * 128, n0 = blockIdx.y * 128;
  const int t = threadIdx.x, lane = t & 63, w = t >> 6;
  const int wr = w >> 1, wc = w & 1, lr = lane & 15, hi = lane >> 4;
  f32x4 acc[4][4] = {};
  for (int d0 = 0; d0 < 512; d0 += 64){
    // A tile: f32 -> bf16 convert during staging (HW cvt_pk)
    #pragma unroll
    for (int p = 0; p < 8; p++){
      int r = p * 16 + (t >> 4), c4 = (t & 15) * 4;
      float4 v = *(const float4*)&X[(m0 + r) * 512 + d0 + c4];
      uint2 pk2; pk2.x = cvtpk(v.x, v.y); pk2.y = cvtpk(v.z, v.w);
      *(uint2*)&sm[0][r][c4] = pk2;
    }
    #pragma unroll
    for (int p = 0; p < 4; p++){
      int r = p * 32 + (t >> 3), ch = (t & 7) * 8;
      *(uint4*)&sm[1][r][ch] = *(const uint4*)&W[(n0 + r) * 512 + d0 + ch];
    }
    __syncthreads();
    #pragma unroll
    for (int kc = 0; kc < 2; kc++){
      bf16x8 a[4], b[4];
      #pragma unroll
      for (int i = 0; i < 4; i++){
        a[i] = as_bf8(*(const uint4*)&sm[0][wr*64 + i*16 + lr][kc*32 + hi*8]);
        b[i] = as_bf8(*(const uint4*)&sm[1][wc*64 + i*16 + lr][kc*32 + hi*8]);
      }
      #pragma unroll
      for (int i = 0; i < 4; i++)
        #pragma unroll
        for (int j = 0; j < 4; j++)
          acc[i][j] = __builtin_amdgcn_mfma_f32_16x16x32_bf16(a[i], b[j], acc[i][j], 0, 0, 0);
    }
    __syncthreads();
  }
  const float* bias = (mode == 0) ? bq : (mode == 1) ? bk : bv;
  float bv4[4];
  #pragma unroll
  for (int j = 0; j < 4; j++) bv4[j] = bias[n0 + wc*64 + j*16 + lr];

  if (mode < 2){
    u16* Out = (mode == 0) ? Qo : Ko;
    const float scale = (mode == 0) ? (0.17677669529663687f * LOG2E) : 1.0f;
    u16* ep = &sm[0][0][0] + w * 4608;   // 64 x 72 region per wave
    #pragma unroll
    for (int i = 0; i < 4; i++)
      #pragma unroll
      for (int j = 0; j < 4; j++)
        #pragma unroll
        for (int r = 0; r < 4; r++){
          float v = (acc[i][j][r] + bv4[j]) * scale;
          ep[(i*16 + hi*4 + r) * 72 + j*16 + lr] = f2bf(v);
        }
    __syncthreads();   // order u16 stores vs uint4 readback
    #pragma unroll
    for (int p = 0; p < 8; p++){
      int rr = p * 8 + (lane >> 3), cc = (lane & 7) * 8;
      uint4 v = *(uint4*)&ep[rr * 72 + cc];
      int gm = m0 + wr*64 + rr;   // row -> (b,s)
      int gc = n0 + wc*64 + cc;   // col -> (n,k)
      int b = gm >> 10, s = gm & 1023, n = gc >> 5, kk = gc & 31;
      *(uint4*)&Out[((b*16 + n)*1024 + s)*32 + kk] = v;
    }
  } else {
    // V transposed: Vt[((b*16+n)*32 + k)*1024 + s]
    #pragma unroll
    for (int i = 0; i < 4; i++)
      #pragma unroll
      for (int j = 0; j < 4; j++){
        int gm = m0 + wr*64 + i*16 + hi*4;  // 4 consecutive s
        int gc = n0 + wc*64 + j*16 + lr;
        int b = gm >> 10, s = gm & 1023, n = gc >> 5, kk = gc & 31;
        uint2 vv;
        vv.x = cvtpk(acc[i][j][0] + bv4[j], acc[i][j][1] + bv4[j]);
        vv.y = cvtpk(acc[i][j][2] + bv4[j], acc[i][j][3] + bv4[j]);
        *(uint2*)&Vt[(((b*16 + n)*32 + kk) * 1024) + s] = vv;
      }
  }
}

// ---------------------------------------------------------------------------
// K2: attention, in-block split-K. 1024 blocks (XCD-swizzled) x 512 threads
// = 8 waves: waves 0-3 do t in [0,512) for q-tiles 0-3; waves 4-7 do
// t in [512,1024). No-max exp2 softmax => partial (oacc, lsum) are directly
// addable; combine via LDS at the end. 32 waves/CU => 100% occupancy ceiling.
// ---------------------------------------------------------------------------
__global__ __launch_bounds__(512) void k_attn(
    const u16* __restrict__ Q, const u16* __restrict__ Kg,
    const u16* __restrict__ Vt, const float* __restrict__ relb,
    u16* __restrict__ AO)
{
  __shared__ float bias_s[63 * 63];
  __shared__ float cm[4][16][64];
  __shared__ float lsum_s[4][32];
  const int t = threadIdx.x, lane = t & 63, w8 = t >> 6;
  const int wg = w8 & 3, half = w8 >> 2;
  const int hi = lane >> 5, lq = lane & 31;
  const int bid = ((blockIdx.x & 7) << 7) | (blockIdx.x >> 3);  // XCD swizzle
  const int qt = bid & 7, bn = bid >> 3, n = bn & 15;
  const int q0 = qt * 128 + wg * 32;
  const u16* Qp = Q  + (bn * 1024 + q0) * 32;
  const u16* Kp = Kg + bn * 1024 * 32;
  const u16* Vp = Vt + bn * 32 * 1024;
  const float* rb = relb + n * 63 * 63;
  // bias in exp2 domain, minus safety C=8 (softmax shift-invariant)
  for (int i = t; i < 63 * 63; i += 512) bias_s[i] = rb[i] * LOG2E - 8.0f;

  bf16x8 qf[2];
  #pragma unroll
  for (int kc = 0; kc < 2; kc++)
    qf[kc] = as_bf8(*(const uint4*)&Qp[lq*32 + kc*16 + hi*8]);
  const int h_q = q0 >> 5;
  __syncthreads();

  f32x16 oacc = {};
  float ls0 = 0.f, ls1 = 0.f;

  const int tbeg = half * 512, tend = tbeg + 512;
  for (int t0 = tbeg; t0 < tend; t0 += 64){
    uint4 kv[4], vv[4];
    #pragma unroll
    for (int ts = 0; ts < 2; ts++){
      kv[ts*2+0] = *(const uint4*)&Kp[(t0 + ts*32 + lq)*32 + hi*8];
      kv[ts*2+1] = *(const uint4*)&Kp[(t0 + ts*32 + lq)*32 + 16 + hi*8];
    }
    #pragma unroll
    for (int tc = 0; tc < 4; tc++)
      vv[tc] = *(const uint4*)&Vp[lq*1024 + t0 + tc*16 + hi*8];

    u32 pk[16];
    #pragma unroll
    for (int ts = 0; ts < 2; ts++){
      f32x16 c = {};
      c = __builtin_amdgcn_mfma_f32_32x32x16_bf16(as_bf8(kv[ts*2+0]), qf[0], c, 0, 0, 0);
      c = __builtin_amdgcn_mfma_f32_32x32x16_bf16(as_bf8(kv[ts*2+1]), qf[1], c, 0, 0, 0);
      const int dh = h_q - (t0 >> 5) - ts + 31;                // wave-uniform
      const int bbase = dh * 63 + 31 + lq - hi * 4;            // dw = bbase - tl
      #pragma unroll
      for (int r = 0; r < 16; r += 2){
        int tl = (r & 3) + 8 * (r >> 2);
        float v0 = EXP2(c[r]   + bias_s[bbase - tl]);
        float v1 = EXP2(c[r+1] + bias_s[bbase - tl - 1]);
        ls0 += v0; ls1 += v1;
        pk[ts*8 + (r >> 1)] = cvtpk(v0, v1);
      }
    }
    // PV: B-fragment for tc from pairs (4tc,4tc+2),(4tc+1,4tc+3) via permlane swap
    #pragma unroll
    for (int tc = 0; tc < 4; tc++){
      u32 a0 = pk[tc*4+0], b0 = pk[tc*4+2];
      u32 a1 = pk[tc*4+1], b1 = pk[tc*4+3];
      plswap(a0, b0);
      plswap(a1, b1);
      uint4 bb; bb.x = a0; bb.y = a1; bb.z = b0; bb.w = b1;
      oacc = __builtin_amdgcn_mfma_f32_32x32x16_bf16(as_bf8(vv[tc]), as_bf8(bb), oacc, 0, 0, 0);
    }
  }
  float lsum = ls0 + ls1;
  lsum += __shfl_xor(lsum, 32);

  // split-K combine: upper half dumps partials; lower half adds + stores.
  if (half){
    #pragma unroll
    for (int i = 0; i < 16; i++) cm[wg][i][lane] = oacc[i];
    if (lane < 32) lsum_s[wg][lane] = lsum;
  }
  __syncthreads();
  if (!half){
    #pragma unroll
    for (int i = 0; i < 16; i++) oacc[i] += cm[wg][i][lane];
    lsum += lsum_s[wg][lq];
    float inv = 1.0f / lsum;
    const int b = bn >> 4;
    u16* op = AO + ((b * 1024 + q0 + lq) * 16 + n) * 32;
    #pragma unroll
    for (int g = 0; g < 4; g++){
      uint2 vv2;
      vv2.x = cvtpk(oacc[g*4+0] * inv, oacc[g*4+1] * inv);
      vv2.y = cvtpk(oacc[g*4+2] * inv, oacc[g*4+3] * inv);
      *(uint2*)&op[g*8 + hi*4] = vv2;
    }
  }
}

// ---------------------------------------------------------------------------
// K3: output projection. attn(bf16) [8192][512] x WoT(bf16) -> out(F32) + bo
// ---------------------------------------------------------------------------
__global__ __launch_bounds__(256) void k_out(
    const u16* __restrict__ Ain, const u16* __restrict__ WoT,
    const float* __restrict__ bo, float* __restrict__ Out)
{
  __shared__ u16 sm[2][128][72];
  const int m0 = blockIdx.x * 128, n0 = blockIdx.y * 128;
  const int t = threadIdx.x, lane = t & 63, w = t >> 6;
  const int wr = w >> 1, wc = w & 1, lr = lane & 15, hi = lane >> 4;
  f32x4 acc[4][4] = {};
  for (int d0 = 0; d0 < 512; d0 += 64){
    #pragma unroll
    for (int p = 0; p < 4; p++){
      int r = p * 32 + (t >> 3), ch = (t & 7) * 8;
      *(uint4*)&sm[0][r][ch] = *(const uint4*)&Ain[(m0 + r) * 512 + d0 + ch];
      *(uint4*)&sm[1][r][ch] = *(const uint4*)&WoT[(n0 + r) * 512 + d0 + ch];
    }
    __syncthreads();
    #pragma unroll
    for (int kc = 0; kc < 2; kc++){
      bf16x8 a[4], b[4];
      #pragma unroll
      for (int i = 0; i < 4; i++){
        a[i] = as_bf8(*(const uint4*)&sm[0][wr*64 + i*16 + lr][kc*32 + hi*8]);
        b[i] = as_bf8(*(const uint4*)&sm[1][wc*64 + i*16 + lr][kc*32 + hi*8]);
      }
      #pragma unroll
      for (int i = 0; i < 4; i++)
        #pragma unroll
        for (int j = 0; j < 4; j++)
          acc[i][j] = __builtin_amdgcn_mfma_f32_16x16x32_bf16(a[i], b[j], acc[i][j], 0, 0, 0);
    }
    __syncthreads();
  }
  float bv4[4];
  #pragma unroll
  for (int j = 0; j < 4; j++) bv4[j] = bo[n0 + wc*64 + j*16 + lr];
  #pragma unroll
  for (int i = 0; i < 4; i++)
    #pragma unroll
    for (int j = 0; j < 4; j++)
      #pragma unroll
      for (int r = 0; r < 4; r++)
        Out[(m0 + wr*64 + i*16 + hi*4 + r) * 512 + n0 + wc*64 + j*16 + lr]
            = acc[i][j][r] + bv4[j];
}

// ---------------------------------------------------------------------------
extern "C" void kernel_launch(void* const* d_in, const int* in_sizes, int n_in,
                              void* d_out, int out_size, void* d_ws, size_t ws_size,
                              hipStream_t stream)
{
  const float* query = (const float*)d_in[0];
  const float* Wq    = (const float*)d_in[1];
  const float* bq    = (const float*)d_in[2];
  const float* Wk    = (const float*)d_in[3];
  const float* bk    = (const float*)d_in[4];
  const float* Wv    = (const float*)d_in[5];
  const float* bv    = (const float*)d_in[6];
  const float* Wo    = (const float*)d_in[7];
  const float* bo    = (const float*)d_in[8];
  const float* relb  = (const float*)d_in[9];
  float* out = (float*)d_out;

  u16* WT  = (u16*)d_ws;                       // 4 * 512*512 bf16
  u16* Qw  = WT  + 4 * 512 * 512;              // 8*16*1024*32 bf16 each
  u16* Kw  = Qw  + 8 * 16 * 1024 * 32;
  u16* Vtw = Kw  + 8 * 16 * 1024 * 32;
  u16* Aw  = Vtw + 8 * 16 * 1024 * 32;

  k_wtrans<<<dim3(8, 8, 4), dim3(256), 0, stream>>>(Wq, Wk, Wv, Wo, WT);
  k_qkv  <<<dim3(64, 4, 3), dim3(256), 0, stream>>>(query, WT, bq, bk, bv, Qw, Kw, Vtw);
  k_attn <<<dim3(1024),     dim3(512), 0, stream>>>(Qw, Kw, Vtw, relb, Aw);
  k_out  <<<dim3(64, 4),    dim3(256), 0, stream>>>(Aw, WT + 3 * 512 * 512, bo, out);
}